// Round 5
// baseline (3367.682 us; speedup 1.0000x reference)
//
#include <hip/hip_runtime.h>
#include <hip/hip_bf16.h>
#include <cstdint>
#include <cstddef>

#define M_DIM 8192
#define K_DIM 4096
#define N_DIM 4096
#define EPS 1e-5f

typedef __bf16 bf16x8 __attribute__((ext_vector_type(8)));
typedef unsigned short u16x8 __attribute__((ext_vector_type(8)));
typedef float f32x4 __attribute__((ext_vector_type(4)));

// ---------- helpers ----------

__device__ __forceinline__ unsigned short f2bf(float f) {
  unsigned int u = __builtin_bit_cast(unsigned int, f);
  u += 0x7fffu + ((u >> 16) & 1u);   // round-to-nearest-even
  return (unsigned short)(u >> 16);
}

// GELU(tanh-approx)+ReLU via identity 0.5y(1+tanh(w)) = y*sigmoid(2w):
// ge = y / (1 + exp2(-c2*z)), z = y + 0.044715 y^3, c2 = 2*0.7978845608*log2(e)
__device__ __forceinline__ float fused_epilogue(float acc, float inv, float shift) {
  float y = fmaf(acc, inv, shift);
  float y2 = y * y;
  float z = fmaf(0.044715f * y2, y, y);
  float e = __builtin_amdgcn_exp2f(-2.3022081f * z);
  float ge = y * __builtin_amdgcn_rcpf(1.0f + e);
  return fmaxf(ge, 0.0f);
}

__device__ __forceinline__ void gload_lds16(const void* gsrc, void* ldst) {
  __builtin_amdgcn_global_load_lds(
      (const __attribute__((address_space(1))) void*)gsrc,
      (__attribute__((address_space(3))) void*)ldst,
      16, 0, 0);
}

// ---------- pre-pass: fp32 -> bf16 conversions ----------

__global__ __launch_bounds__(256) void cvt_x_kernel(const float* __restrict__ x,
                                                    unsigned short* __restrict__ xb) {
  size_t i = ((size_t)blockIdx.x * 256 + threadIdx.x) * 8;
  float4 a = *reinterpret_cast<const float4*>(x + i);
  float4 b = *reinterpret_cast<const float4*>(x + i + 4);
  u16x8 o;
  o[0] = f2bf(a.x); o[1] = f2bf(a.y); o[2] = f2bf(a.z); o[3] = f2bf(a.w);
  o[4] = f2bf(b.x); o[5] = f2bf(b.y); o[6] = f2bf(b.z); o[7] = f2bf(b.w);
  *reinterpret_cast<u16x8*>(xb + i) = o;
}

// W [K][N] fp32 -> Wt [N][K] bf16 (transpose + convert)
__global__ __launch_bounds__(256) void cvt_w_transpose(const float* __restrict__ W,
                                                       unsigned short* __restrict__ Wt) {
  __shared__ float tile[32][33];
  const int tx = threadIdx.x & 31;
  const int tg = threadIdx.x >> 5;
  const int n0 = blockIdx.x * 32;
  const int k0 = blockIdx.y * 32;
#pragma unroll
  for (int j = 0; j < 4; ++j) {
    int k = tg * 4 + j;
    tile[k][tx] = W[(size_t)(k0 + k) * N_DIM + n0 + tx];
  }
  __syncthreads();
#pragma unroll
  for (int j = 0; j < 4; ++j) {
    int n = tg * 4 + j;
    Wt[(size_t)(n0 + n) * K_DIM + k0 + tx] = f2bf(tile[tx][n]);
  }
}

// ---------- main GEMM: 512x256 tile, BK=32, 16 waves, triple-buffered ring ----------
// A [M][K] bf16, Bt [N][K] bf16. LDS rings: A 3x16384 elems, B 3x8192 elems.
// Layout: [rows][32 k-elems], col8' = col8 ^ (row&3) swizzle (pre-swizzled global
// source, linear gload-lds dest, swizzled ds_read address).
// Per tile T: stage tile T+2 -> slot (T+2)%3 (its readers drained at T-1's end
// barrier); read slot T%3; 32 MFMA; lgkm(0); vmcnt(3) keeps T+2's 3 loads in
// flight; ONE barrier.

#define SA0 0
#define SA1 16384
#define SA2 32768
#define SB0 49152
#define SB1 57344
#define SB2 65536

#define KT(T, AR, BR, AW, BW, ST, VM) do {                                         \
  if (ST) {                                                                        \
    gload_lds16(aP + (size_t)((T) + 2) * 32,                 &lds[(AW) + wv512]);  \
    gload_lds16(aP + 256 * (size_t)K_DIM + (size_t)((T) + 2) * 32,                 \
                &lds[(AW) + 8192 + wv512]);                                        \
    gload_lds16(bP + (size_t)((T) + 2) * 32,                 &lds[(BW) + wv512]);  \
  }                                                                                \
  asm volatile("" ::: "memory");                                                   \
  bf16x8 bq[4], aq[8];                                                             \
  _Pragma("unroll") for (int ni = 0; ni < 4; ++ni)                                 \
    bq[ni] = __builtin_bit_cast(bf16x8,                                            \
        *(const u16x8*)&lds[(BR) + bBase + ni * 512]);                             \
  _Pragma("unroll") for (int mi = 0; mi < 8; ++mi)                                 \
    aq[mi] = __builtin_bit_cast(bf16x8,                                            \
        *(const u16x8*)&lds[(AR) + aBase + mi * 512]);                             \
  __builtin_amdgcn_s_setprio(1);                                                   \
  _Pragma("unroll") for (int mi = 0; mi < 8; ++mi)                                 \
  _Pragma("unroll") for (int ni = 0; ni < 4; ++ni)                                 \
    acc[mi][ni] = __builtin_amdgcn_mfma_f32_16x16x32_bf16(aq[mi], bq[ni],          \
                                                          acc[mi][ni], 0, 0, 0);   \
  __builtin_amdgcn_s_setprio(0);                                                   \
  if ((VM) >= 0) {                                                                 \
    asm volatile("s_waitcnt lgkmcnt(0)" ::: "memory");                             \
    if ((VM) == 3)      asm volatile("s_waitcnt vmcnt(3)" ::: "memory");           \
    else                asm volatile("s_waitcnt vmcnt(0)" ::: "memory");           \
    __builtin_amdgcn_s_barrier();                                                  \
  }                                                                                \
} while (0)

__global__ __launch_bounds__(1024, 1) void gemm_bf16_fused(
    const unsigned short* __restrict__ A,
    const unsigned short* __restrict__ Bt,
    const float* __restrict__ gam, const float* __restrict__ bet,
    const float* __restrict__ mu, const float* __restrict__ var,
    float* __restrict__ C) {
  __shared__ __align__(16) unsigned short lds[73728];  // 144 KiB

  const int tid = threadIdx.x;
  const int wave = tid >> 6;
  const int lane = tid & 63;
  const int l15 = lane & 15, l4 = lane >> 4;
  const int wr = wave >> 2, wc = wave & 3;   // 4x4 wave grid; per-wave out 128x64
  const int wv512 = wave * 512;

  // XCD-aware swizzle: 256 blocks, 256 % 8 == 0 -> bijective
  const int bid = (int)blockIdx.x;
  const int swz = (bid & 7) * 32 + (bid >> 3);
  const int bx = swz & 15;                   // 16 N-tiles (256 each)
  const int by = swz >> 4;                   // 16 M-tiles (512 each)
  const size_t bm = (size_t)by * 512;
  const size_t bn = (size_t)bx * 256;

  // stage source pointers (pre-swizzled per lane; gload-lds dest linear)
  const int srow = lane >> 2;                // 0..15 within wave's 16-row group
  const int scol = (lane & 3) ^ (srow & 3);  // swizzled col8
  const unsigned short* aP = A  + (bm + (size_t)(wave * 16 + srow)) * K_DIM + scol * 8;
  const unsigned short* bP = Bt + (bn + (size_t)(wave * 16 + srow)) * K_DIM + scol * 8;

  // ds_read per-lane bases (u16 elem units); xk = (l4 ^ (row&3))*8, row&3 == l15&3
  const int xk = ((l4 ^ (l15 & 3)) * 8);
  const int aBase = (wr * 128 + l15) * 32 + xk;
  const int bBase = (wc * 64  + l15) * 32 + xk;

  f32x4 acc[8][4] = {};

  // ---- prologue: stage tiles 0 -> slot0, 1 -> slot1 (order pinned) ----
  gload_lds16(aP,                        &lds[SA0 + wv512]);
  gload_lds16(aP + 256 * (size_t)K_DIM,  &lds[SA0 + 8192 + wv512]);
  gload_lds16(bP,                        &lds[SB0 + wv512]);
  asm volatile("" ::: "memory");
  gload_lds16(aP + 32,                       &lds[SA1 + wv512]);
  gload_lds16(aP + 256 * (size_t)K_DIM + 32, &lds[SA1 + 8192 + wv512]);
  gload_lds16(bP + 32,                       &lds[SB1 + wv512]);
  asm volatile("s_waitcnt vmcnt(3)" ::: "memory");   // tile 0 landed; tile 1 in flight
  __builtin_amdgcn_s_barrier();

  // ---- main loop: 128 K-tiles (BK=32), x3 unroll for ring slots ----
  for (int t = 0; t < 126; t += 3) {
    KT(t,     SA0, SB0, SA2, SB2, 1, 3);
    KT(t + 1, SA1, SB1, SA0, SB0, 1, 3);
    KT(t + 2, SA2, SB2, SA1, SB1, 1, 3);
  }
  KT(126, SA0, SB0, 0, 0, 0, 0);    // no stage; drain (tile 127 must land)
  KT(127, SA1, SB1, 0, 0, 0, -1);   // last tile, no barrier

  // ---- epilogue: fused BN + GELU + ReLU ----
  const int row0 = (int)bm + wr * 128;
  const int col0 = (int)bn + wc * 64;
#pragma unroll
  for (int ni = 0; ni < 4; ++ni) {
    const int col = col0 + ni * 16 + l15;
    const float inv = rsqrtf(var[col] + EPS) * gam[col];
    const float shift = fmaf(-mu[col], inv, bet[col]);
#pragma unroll
    for (int mi = 0; mi < 8; ++mi) {
      const int r0 = row0 + mi * 16 + l4 * 4;
#pragma unroll
      for (int r = 0; r < 4; ++r)
        C[(size_t)(r0 + r) * N_DIM + col] = fused_epilogue(acc[mi][ni][r], inv, shift);
    }
  }
}

// ---------- fallback (only if ws too small): fp32 tiled GEMM ----------

__global__ __launch_bounds__(256) void gemm_f32_fallback(
    const float* __restrict__ A, const float* __restrict__ W,
    const float* __restrict__ gam, const float* __restrict__ bet,
    const float* __restrict__ mu, const float* __restrict__ var,
    float* __restrict__ C) {
  __shared__ float As[16][65];
  __shared__ float Bs[16][65];
  const int tid = threadIdx.x;
  const int tx = tid & 15, ty = tid >> 4;
  const int bn0 = blockIdx.x * 64, bm0 = blockIdx.y * 64;
  float acc[4][4] = {};
  for (int k0 = 0; k0 < K_DIM; k0 += 16) {
#pragma unroll
    for (int j = 0; j < 4; ++j)
      As[tid & 15][(tid >> 4) * 4 + j] =
          A[(size_t)(bm0 + (tid >> 4) * 4 + j) * K_DIM + k0 + (tid & 15)];
#pragma unroll
    for (int j = 0; j < 4; ++j)
      Bs[tid >> 4][(tid & 15) * 4 + j] =
          W[(size_t)(k0 + (tid >> 4)) * N_DIM + bn0 + (tid & 15) * 4 + j];
    __syncthreads();
#pragma unroll
    for (int kk = 0; kk < 16; ++kk) {
      float a_[4], b_[4];
#pragma unroll
      for (int i = 0; i < 4; ++i) a_[i] = As[kk][ty * 4 + i];
#pragma unroll
      for (int j = 0; j < 4; ++j) b_[j] = Bs[kk][tx * 4 + j];
#pragma unroll
      for (int i = 0; i < 4; ++i)
#pragma unroll
        for (int j = 0; j < 4; ++j)
          acc[i][j] = fmaf(a_[i], b_[j], acc[i][j]);
    }
    __syncthreads();
  }
#pragma unroll
  for (int j = 0; j < 4; ++j) {
    const int col = bn0 + tx * 4 + j;
    const float inv = rsqrtf(var[col] + EPS) * gam[col];
    const float shift = fmaf(-mu[col], inv, bet[col]);
#pragma unroll
    for (int i = 0; i < 4; ++i) {
      float y = fmaf(acc[i][j], inv, shift);
      float y2 = y * y;
      float z = fmaf(0.044715f * y2, y, y);
      float e = __builtin_amdgcn_exp2f(-2.3022081f * z);
      float ge = y * __builtin_amdgcn_rcpf(1.0f + e);
      C[(size_t)(bm0 + ty * 4 + i) * N_DIM + col] = fmaxf(ge, 0.0f);
    }
  }
}

// ---------- launch ----------

extern "C" void kernel_launch(void* const* d_in, const int* in_sizes, int n_in,
                              void* d_out, int out_size, void* d_ws, size_t ws_size,
                              hipStream_t stream) {
  const float* x  = (const float*)d_in[0];
  const float* w  = (const float*)d_in[1];
  const float* gg = (const float*)d_in[2];
  const float* bb = (const float*)d_in[3];
  const float* mu = (const float*)d_in[4];
  const float* vr = (const float*)d_in[5];
  float* out = (float*)d_out;

  const size_t xb_bytes = (size_t)M_DIM * K_DIM * 2;
  const size_t wt_bytes = (size_t)K_DIM * N_DIM * 2;

  if (ws_size >= xb_bytes + wt_bytes) {
    unsigned short* xb = (unsigned short*)d_ws;
    unsigned short* wt = xb + (size_t)M_DIM * K_DIM;
    cvt_x_kernel<<<dim3((M_DIM * (size_t)K_DIM) / 8 / 256), dim3(256), 0, stream>>>(x, xb);
    cvt_w_transpose<<<dim3(N_DIM / 32, K_DIM / 32), dim3(256), 0, stream>>>(w, wt);
    gemm_bf16_fused<<<dim3((M_DIM / 512) * (N_DIM / 256)), dim3(1024), 0, stream>>>(
        xb, wt, gg, bb, mu, vr, out);
  } else {
    gemm_f32_fallback<<<dim3(N_DIM / 64, M_DIM / 64), dim3(256), 0, stream>>>(
        x, w, gg, bb, mu, vr, out);
  }
}

// Round 6
// 290.968 us; speedup vs baseline: 11.5741x; 11.5741x over previous
//
#include <hip/hip_runtime.h>
#include <hip/hip_bf16.h>
#include <cstdint>
#include <cstddef>

#define M_DIM 8192
#define K_DIM 4096
#define N_DIM 4096
#define EPS 1e-5f

typedef __bf16 bf16x8 __attribute__((ext_vector_type(8)));
typedef unsigned short u16x8 __attribute__((ext_vector_type(8)));
typedef float f32x4 __attribute__((ext_vector_type(4)));

// ---------- helpers ----------

__device__ __forceinline__ unsigned short f2bf(float f) {
  unsigned int u = __builtin_bit_cast(unsigned int, f);
  u += 0x7fffu + ((u >> 16) & 1u);   // round-to-nearest-even
  return (unsigned short)(u >> 16);
}

// GELU(tanh-approx)+ReLU via identity 0.5y(1+tanh(w)) = y*sigmoid(2w):
// ge = y / (1 + exp2(-c2*z)), z = y + 0.044715 y^3, c2 = 2*0.7978845608*log2(e)
__device__ __forceinline__ float fused_epilogue(float acc, float inv, float shift) {
  float y = fmaf(acc, inv, shift);
  float y2 = y * y;
  float z = fmaf(0.044715f * y2, y, y);
  float e = __builtin_amdgcn_exp2f(-2.3022081f * z);
  float ge = y * __builtin_amdgcn_rcpf(1.0f + e);
  return fmaxf(ge, 0.0f);
}

__device__ __forceinline__ void gload_lds16(const void* gsrc, void* ldst) {
  __builtin_amdgcn_global_load_lds(
      (const __attribute__((address_space(1))) void*)gsrc,
      (__attribute__((address_space(3))) void*)ldst,
      16, 0, 0);
}

// ---------- pre-pass: fp32 -> bf16 conversions ----------

__global__ __launch_bounds__(256) void cvt_x_kernel(const float* __restrict__ x,
                                                    unsigned short* __restrict__ xb) {
  size_t i = ((size_t)blockIdx.x * 256 + threadIdx.x) * 8;
  float4 a = *reinterpret_cast<const float4*>(x + i);
  float4 b = *reinterpret_cast<const float4*>(x + i + 4);
  u16x8 o;
  o[0] = f2bf(a.x); o[1] = f2bf(a.y); o[2] = f2bf(a.z); o[3] = f2bf(a.w);
  o[4] = f2bf(b.x); o[5] = f2bf(b.y); o[6] = f2bf(b.z); o[7] = f2bf(b.w);
  *reinterpret_cast<u16x8*>(xb + i) = o;
}

// W [K][N] fp32 -> Wt [N][K] bf16 (transpose + convert)
__global__ __launch_bounds__(256) void cvt_w_transpose(const float* __restrict__ W,
                                                       unsigned short* __restrict__ Wt) {
  __shared__ float tile[32][33];
  const int tx = threadIdx.x & 31;
  const int tg = threadIdx.x >> 5;
  const int n0 = blockIdx.x * 32;
  const int k0 = blockIdx.y * 32;
#pragma unroll
  for (int j = 0; j < 4; ++j) {
    int k = tg * 4 + j;
    tile[k][tx] = W[(size_t)(k0 + k) * N_DIM + n0 + tx];
  }
  __syncthreads();
#pragma unroll
  for (int j = 0; j < 4; ++j) {
    int n = tg * 4 + j;
    Wt[(size_t)(n0 + n) * K_DIM + k0 + tx] = f2bf(tile[tx][n]);
  }
}

// ---------- main GEMM: 256x256 tile, BK=64, 8 waves, 2-barrier K-tile ----------
// Identical hazard structure/ledger to the passing R4 kernel; within each k-half
// segment the ds_reads are software-pipelined against 4-MFMA groups and pinned
// with sched_group_barrier (MFMA=0x8, DS_READ=0x100) per m196/T19.

#define STG_A(h, j, PAR, T)                                                        \
  gload_lds16(aS + (size_t)((h)*128 + 64*(j)) * K_DIM + (size_t)((T) + 1) * 64,    \
              &lds[(2*(1-(PAR)) + (h)) * 8192 + (wave + 8*(j)) * 512])

#define STG_B(h, j, PAR, T)                                                        \
  gload_lds16(bS + (size_t)((h)*128 + 64*(j)) * K_DIM + (size_t)((T) + 2) * 64,    \
              &lds[32768 + (2*(PAR) + (h)) * 8192 + (wave + 8*(j)) * 512])

#define LDS_FRAG(off) __builtin_bit_cast(bf16x8, *(const u16x8*)&lds[(off)])
#define SGB __builtin_amdgcn_sched_group_barrier

#define MF4_K0(mi)                                                                 \
  _Pragma("unroll") for (int ni = 0; ni < 4; ++ni)                                 \
    acc[mi][ni] = __builtin_amdgcn_mfma_f32_16x16x32_bf16(ak0[mi], b0[ni],         \
                                                          acc[mi][ni], 0, 0, 0)
#define MF4_K1(mi)                                                                 \
  _Pragma("unroll") for (int ni = 0; ni < 4; ++ni)                                 \
    acc[mi][ni] = __builtin_amdgcn_mfma_f32_16x16x32_bf16(ak1[mi], b1[ni],         \
                                                          acc[mi][ni], 0, 0, 0)

#define KTILE(T, PAR, STA, STB, VM) do {                                           \
  const int sa = (PAR) * 16384 + saW;                                              \
  const int sb = (PAR) * 16384 + sbW;                                              \
  if (STA) { STG_A(0,0,PAR,T); STG_A(0,1,PAR,T);                                   \
             STG_A(1,0,PAR,T); STG_A(1,1,PAR,T); }                                 \
  asm volatile("" ::: "memory");                                                   \
  bf16x8 b0[4], b1[4], ak0[8], ak1[8];                                             \
  /* ---- segment kh0: 16 reads interleaved with 32 MFMAs ---- */                  \
  b0[0] = LDS_FRAG(sb + bro + 0 * 1024 + xk0);                                     \
  b0[1] = LDS_FRAG(sb + bro + 1 * 1024 + xk0);                                     \
  b0[2] = LDS_FRAG(sb + bro + 2 * 1024 + xk0);                                     \
  b0[3] = LDS_FRAG(sb + bro + 3 * 1024 + xk0);                                     \
  ak0[0] = LDS_FRAG(sa + aro + 0 * 1024 + xk0);                                    \
  ak0[1] = LDS_FRAG(sa + aro + 1 * 1024 + xk0);                                    \
  SGB(0x100, 6, 0);                                                                \
  __builtin_amdgcn_s_setprio(1);                                                   \
  MF4_K0(0); SGB(0x8, 4, 0);                                                       \
  ak0[2] = LDS_FRAG(sa + aro + 2 * 1024 + xk0); SGB(0x100, 1, 0);                  \
  MF4_K0(1); SGB(0x8, 4, 0);                                                       \
  ak0[3] = LDS_FRAG(sa + aro + 3 * 1024 + xk0); SGB(0x100, 1, 0);                  \
  MF4_K0(2); SGB(0x8, 4, 0);                                                       \
  ak0[4] = LDS_FRAG(sa + aro + 4 * 1024 + xk0); SGB(0x100, 1, 0);                  \
  MF4_K0(3); SGB(0x8, 4, 0);                                                       \
  ak0[5] = LDS_FRAG(sa + aro + 5 * 1024 + xk0); SGB(0x100, 1, 0);                  \
  MF4_K0(4); SGB(0x8, 4, 0);                                                       \
  ak0[6] = LDS_FRAG(sa + aro + 6 * 1024 + xk0); SGB(0x100, 1, 0);                  \
  MF4_K0(5); SGB(0x8, 4, 0);                                                       \
  ak0[7] = LDS_FRAG(sa + aro + 7 * 1024 + xk0); SGB(0x100, 1, 0);                  \
  MF4_K0(6); SGB(0x8, 4, 0);                                                       \
  b1[0] = LDS_FRAG(sb + bro + 0 * 1024 + xk1);                                     \
  b1[1] = LDS_FRAG(sb + bro + 1 * 1024 + xk1); SGB(0x100, 2, 0);                   \
  MF4_K0(7); SGB(0x8, 4, 0);                                                       \
  b1[2] = LDS_FRAG(sb + bro + 2 * 1024 + xk1);                                     \
  b1[3] = LDS_FRAG(sb + bro + 3 * 1024 + xk1); SGB(0x100, 2, 0);                   \
  __builtin_amdgcn_s_setprio(0);                                                   \
  asm volatile("s_waitcnt lgkmcnt(0)" ::: "memory");                               \
  __builtin_amdgcn_s_barrier();           /* MID: B(t) fully consumed */           \
  if (STB) { STG_B(0,0,PAR,T); STG_B(0,1,PAR,T);                                   \
             STG_B(1,0,PAR,T); STG_B(1,1,PAR,T); }                                 \
  asm volatile("" ::: "memory");                                                   \
  /* ---- segment kh1: 8 reads interleaved with 32 MFMAs ---- */                   \
  ak1[0] = LDS_FRAG(sa + aro + 0 * 1024 + xk1);                                    \
  ak1[1] = LDS_FRAG(sa + aro + 1 * 1024 + xk1); SGB(0x100, 2, 0);                  \
  __builtin_amdgcn_s_setprio(1);                                                   \
  MF4_K1(0); SGB(0x8, 4, 0);                                                       \
  ak1[2] = LDS_FRAG(sa + aro + 2 * 1024 + xk1); SGB(0x100, 1, 0);                  \
  MF4_K1(1); SGB(0x8, 4, 0);                                                       \
  ak1[3] = LDS_FRAG(sa + aro + 3 * 1024 + xk1); SGB(0x100, 1, 0);                  \
  MF4_K1(2); SGB(0x8, 4, 0);                                                       \
  ak1[4] = LDS_FRAG(sa + aro + 4 * 1024 + xk1); SGB(0x100, 1, 0);                  \
  MF4_K1(3); SGB(0x8, 4, 0);                                                       \
  ak1[5] = LDS_FRAG(sa + aro + 5 * 1024 + xk1); SGB(0x100, 1, 0);                  \
  MF4_K1(4); SGB(0x8, 4, 0);                                                       \
  ak1[6] = LDS_FRAG(sa + aro + 6 * 1024 + xk1); SGB(0x100, 1, 0);                  \
  MF4_K1(5); SGB(0x8, 4, 0);                                                       \
  ak1[7] = LDS_FRAG(sa + aro + 7 * 1024 + xk1); SGB(0x100, 1, 0);                  \
  MF4_K1(6); SGB(0x8, 4, 0);                                                       \
  MF4_K1(7); SGB(0x8, 4, 0);                                                       \
  __builtin_amdgcn_s_setprio(0);                                                   \
  if ((VM) >= 0) {                                                                 \
    asm volatile("s_waitcnt lgkmcnt(0)" ::: "memory");                             \
    if ((VM) == 4)      asm volatile("s_waitcnt vmcnt(4)" ::: "memory");           \
    else                asm volatile("s_waitcnt vmcnt(0)" ::: "memory");           \
    __builtin_amdgcn_s_barrier();         /* END */                                \
  }                                                                                \
} while (0)

__global__ __launch_bounds__(512, 2) void gemm_bf16_fused(
    const unsigned short* __restrict__ A,
    const unsigned short* __restrict__ Bt,
    const float* __restrict__ gam, const float* __restrict__ bet,
    const float* __restrict__ mu, const float* __restrict__ var,
    float* __restrict__ C) {
  __shared__ __align__(16) unsigned short lds[65536];  // 128 KiB

  const int tid = threadIdx.x;
  const int wave = tid >> 6;
  const int lane = tid & 63;
  const int l15 = lane & 15, l4 = lane >> 4;
  const int wr = wave >> 2, wc = wave & 3;   // 2x4 wave grid; per-wave out 128x64

  // XCD-aware swizzle: 512 blocks, 512 % 8 == 0 -> bijective
  const int bid = (int)blockIdx.x;
  const int swz = (bid & 7) * 64 + (bid >> 3);
  const int bx = swz & 15;                   // 16 N-tiles
  const int by = swz >> 4;                   // 32 M-tiles
  const size_t bm = (size_t)by * 256;
  const size_t bn = (size_t)bx * 256;

  // stage source addresses (pre-swizzled global per lane; LDS dest linear)
  const int lr = lane >> 3, lc = lane & 7;
  const unsigned short* aS = A + (bm + (size_t)(wave * 8 + lr)) * K_DIM + (lc ^ lr) * 8;
  const unsigned short* bS = Bt + (bn + (size_t)(wave * 8 + lr)) * K_DIM + (lc ^ lr) * 8;

  // ds_read fragment offsets (u16 units); col8' = col8 ^ (row&7), row&7 == l15&7
  const int xk0 = ((l4)     ^ (l15 & 7)) * 8;
  const int xk1 = ((l4 | 4) ^ (l15 & 7)) * 8;
  const int aro = l15 * 64;
  const int bro = (wc & 1) * 4096 + l15 * 64;
  const int saW = wr * 8192;
  const int sbW = 32768 + (wc >> 1) * 8192;

  f32x4 acc[8][4] = {};

  // ---- prologue: stage A(0), B(0), B(1); wait A(0)+B(0) landed ----
  STG_A(0, 0, 1, -1); STG_A(0, 1, 1, -1);
  STG_A(1, 0, 1, -1); STG_A(1, 1, 1, -1);
  asm volatile("" ::: "memory");
  STG_B(0, 0, 0, -2); STG_B(0, 1, 0, -2);
  STG_B(1, 0, 0, -2); STG_B(1, 1, 0, -2);
  asm volatile("" ::: "memory");
  STG_B(0, 0, 1, -1); STG_B(0, 1, 1, -1);
  STG_B(1, 0, 1, -1); STG_B(1, 1, 1, -1);
  asm volatile("s_waitcnt vmcnt(4)" ::: "memory");
  __builtin_amdgcn_s_barrier();

  // ---- main loop: 64 K-tiles ----
  for (int t = 0; t < 60; t += 2) {
    KTILE(t,     0, 1, 1, 4);
    KTILE(t + 1, 1, 1, 1, 4);
  }
  KTILE(60, 0, 1, 1, 4);
  KTILE(61, 1, 1, 1, 4);   // stages A(62), B(63)
  KTILE(62, 0, 1, 0, 0);   // stages A(63); drain all outstanding
  KTILE(63, 1, 0, 0, -1);  // no stages, nothing outstanding, no end barrier

  // ---- epilogue: fused BN + GELU + ReLU ----
  const int row0 = (int)bm + wr * 128;
  const int col0 = (int)bn + wc * 64;
#pragma unroll
  for (int ni = 0; ni < 4; ++ni) {
    const int col = col0 + ni * 16 + l15;
    const float inv = rsqrtf(var[col] + EPS) * gam[col];
    const float shift = fmaf(-mu[col], inv, bet[col]);
#pragma unroll
    for (int mi = 0; mi < 8; ++mi) {
      const int r0 = row0 + mi * 16 + l4 * 4;
#pragma unroll
      for (int r = 0; r < 4; ++r)
        C[(size_t)(r0 + r) * N_DIM + col] = fused_epilogue(acc[mi][ni][r], inv, shift);
    }
  }
}

// ---------- fallback (only if ws too small): fp32 tiled GEMM ----------

__global__ __launch_bounds__(256) void gemm_f32_fallback(
    const float* __restrict__ A, const float* __restrict__ W,
    const float* __restrict__ gam, const float* __restrict__ bet,
    const float* __restrict__ mu, const float* __restrict__ var,
    float* __restrict__ C) {
  __shared__ float As[16][65];
  __shared__ float Bs[16][65];
  const int tid = threadIdx.x;
  const int tx = tid & 15, ty = tid >> 4;
  const int bn0 = blockIdx.x * 64, bm0 = blockIdx.y * 64;
  float acc[4][4] = {};
  for (int k0 = 0; k0 < K_DIM; k0 += 16) {
#pragma unroll
    for (int j = 0; j < 4; ++j)
      As[tid & 15][(tid >> 4) * 4 + j] =
          A[(size_t)(bm0 + (tid >> 4) * 4 + j) * K_DIM + k0 + (tid & 15)];
#pragma unroll
    for (int j = 0; j < 4; ++j)
      Bs[tid >> 4][(tid & 15) * 4 + j] =
          W[(size_t)(k0 + (tid >> 4)) * N_DIM + bn0 + (tid & 15) * 4 + j];
    __syncthreads();
#pragma unroll
    for (int kk = 0; kk < 16; ++kk) {
      float a_[4], b_[4];
#pragma unroll
      for (int i = 0; i < 4; ++i) a_[i] = As[kk][ty * 4 + i];
#pragma unroll
      for (int j = 0; j < 4; ++j) b_[j] = Bs[kk][tx * 4 + j];
#pragma unroll
      for (int i = 0; i < 4; ++i)
#pragma unroll
        for (int j = 0; j < 4; ++j)
          acc[i][j] = fmaf(a_[i], b_[j], acc[i][j]);
    }
    __syncthreads();
  }
#pragma unroll
  for (int j = 0; j < 4; ++j) {
    const int col = bn0 + tx * 4 + j;
    const float inv = rsqrtf(var[col] + EPS) * gam[col];
    const float shift = fmaf(-mu[col], inv, bet[col]);
#pragma unroll
    for (int i = 0; i < 4; ++i) {
      float y = fmaf(acc[i][j], inv, shift);
      float y2 = y * y;
      float z = fmaf(0.044715f * y2, y, y);
      float e = __builtin_amdgcn_exp2f(-2.3022081f * z);
      float ge = y * __builtin_amdgcn_rcpf(1.0f + e);
      C[(size_t)(bm0 + ty * 4 + i) * N_DIM + col] = fmaxf(ge, 0.0f);
    }
  }
}

// ---------- launch ----------

extern "C" void kernel_launch(void* const* d_in, const int* in_sizes, int n_in,
                              void* d_out, int out_size, void* d_ws, size_t ws_size,
                              hipStream_t stream) {
  const float* x  = (const float*)d_in[0];
  const float* w  = (const float*)d_in[1];
  const float* gg = (const float*)d_in[2];
  const float* bb = (const float*)d_in[3];
  const float* mu = (const float*)d_in[4];
  const float* vr = (const float*)d_in[5];
  float* out = (float*)d_out;

  const size_t xb_bytes = (size_t)M_DIM * K_DIM * 2;
  const size_t wt_bytes = (size_t)K_DIM * N_DIM * 2;

  if (ws_size >= xb_bytes + wt_bytes) {
    unsigned short* xb = (unsigned short*)d_ws;
    unsigned short* wt = xb + (size_t)M_DIM * K_DIM;
    cvt_x_kernel<<<dim3((M_DIM * (size_t)K_DIM) / 8 / 256), dim3(256), 0, stream>>>(x, xb);
    cvt_w_transpose<<<dim3(N_DIM / 32, K_DIM / 32), dim3(256), 0, stream>>>(w, wt);
    gemm_bf16_fused<<<dim3((M_DIM / 256) * (N_DIM / 256)), dim3(512), 0, stream>>>(
        xb, wt, gg, bb, mu, vr, out);
  } else {
    gemm_f32_fallback<<<dim3(N_DIM / 64, M_DIM / 64), dim3(256), 0, stream>>>(
        x, w, gg, bb, mu, vr, out);
  }
}